// Round 9
// baseline (318.420 us; speedup 1.0000x reference)
//
#include <hip/hip_runtime.h>
#include <hip/hip_bf16.h>
#include <math.h>

using bf16 = __hip_bfloat16;
typedef __attribute__((ext_vector_type(8))) short short8;
typedef __attribute__((ext_vector_type(4))) float f32x4;
typedef __attribute__((ext_vector_type(4))) unsigned int u32x4;

#define BATCH 8192
#define SDIM  70
#define NS    64
#define HID   1024
#define NA    4096
#define KPAD  128   // states K padded 70 -> 128 (multiple of 32 for BK=32)

// async global->LDS, 16 B per lane. LDS dest is wave-uniform base + lane*16.
__device__ __forceinline__ void gld_lds16(const bf16* g, bf16* l) {
    __builtin_amdgcn_global_load_lds(
        (const __attribute__((address_space(1))) void*)g,
        (__attribute__((address_space(3))) void*)l, 16, 0, 0);
}

__device__ __forceinline__ short f2bf(float v) {
    union { bf16 b; short s; } u; u.b = __float2bfloat16(v); return u.s;
}

// ---------------- fused prep kernel ----------------
// block ranges:
//   [0,512)       : states fp32[8192][70] -> bf16[8192][128] zero-padded (8 cols/thread)
//   [512,640)     : W1 [70][1024]   -> w1bt [1024][128]
//   [640,1664)    : W2 [1024][1024] -> w2bt [1024][1024]
//   [1664,5760)   : Wh [1024][4096] -> whbt [4096][1024]
//   [5760,5776)   : pact (5-bit x6 SWAR pack of action_space)
//   [5776,5808)   : trow (5-bit x6 SWAR pack of floor(waitlist) per batch row)
__device__ __forceinline__ void tr32(const float* __restrict__ in, bf16* __restrict__ out,
                                     int K, int N, int Kpad, int bx, int by, int t,
                                     float (*tile)[33]) {
    int kb = by * 32, nb = bx * 32;
    int tx = t & 31, ty = t >> 5;
    #pragma unroll
    for (int i = 0; i < 32; i += 8) {
        int k = kb + ty + i, n = nb + tx;
        tile[ty + i][tx] = (k < K) ? in[(size_t)k * N + n] : 0.0f;
    }
    __syncthreads();
    #pragma unroll
    for (int i = 0; i < 32; i += 8) {
        int n = nb + ty + i, k = kb + tx;
        if (k < Kpad) out[(size_t)n * Kpad + k] = __float2bfloat16(tile[tx][ty + i]);
    }
}

__global__ __launch_bounds__(256)
void prep_k(const float* __restrict__ states, const float* __restrict__ W1,
            const float* __restrict__ W2, const float* __restrict__ Wh,
            const int* __restrict__ act,
            bf16* __restrict__ statesb, bf16* __restrict__ w1bt,
            bf16* __restrict__ w2bt, bf16* __restrict__ whbt,
            unsigned* __restrict__ pact, unsigned* __restrict__ trow) {
    __shared__ float tile[32][33];
    const int b = blockIdx.x, t = threadIdx.x;
    if (b < 512) {
        int idx = b * 256 + t;                 // 131072 threads, 8 cols each
        int row = idx >> 4;                    // 16 threads per row
        int c0  = (idx & 15) * 8;
        const float* src = states + (size_t)row * SDIM;
        short8 o;
        #pragma unroll
        for (int i = 0; i < 8; i++) {
            int c = c0 + i;
            o[i] = f2bf((c < SDIM) ? src[c] : 0.0f);
        }
        *(short8*)&statesb[(size_t)row * KPAD + c0] = o;
    } else if (b < 640) {
        int r = b - 512;                       // 32 nb x 4 kb
        tr32(W1, w1bt, SDIM, HID, KPAD, r & 31, r >> 5, t, tile);
    } else if (b < 1664) {
        int r = b - 640;                       // 32 x 32
        tr32(W2, w2bt, HID, HID, HID, r & 31, r >> 5, t, tile);
    } else if (b < 5760) {
        int r = b - 1664;                      // 128 nb x 32 kb
        tr32(Wh, whbt, HID, NA, HID, r & 127, r >> 7, t, tile);
    } else if (b < 5776) {
        int c = (b - 5760) * 256 + t;
        if (c < NA) {
            const int* a = act + c * 6;
            unsigned p = 0;
            #pragma unroll
            for (int i = 0; i < 6; i++) p |= ((unsigned)a[i]) << (5 * i);
            pact[c] = p;
        }
    } else {
        int row = (b - 5776) * 256 + t;        // 32*256 = 8192 rows exactly
        const float* wl = states + (size_t)row * SDIM + NS;
        unsigned T = 0;
        #pragma unroll
        for (int i = 0; i < 6; i++) T |= ((unsigned)(int)wl[i]) << (5 * i);
        trow[row] = T;
    }
}

// ---------------- bf16 MFMA GEMM body: 128xBN tile, BK=32, double-buffered ----------------
// C[M][N] = epilogue(A[M][K] @ BT[N][K]^T + bias)
// MODE 0: tanh -> bf16; MODE 3: raw + log-mask (SWAR feasibility) -> bf16
//
// Pipeline (catalog T3-minimal 2-phase): per 32-k tile
//   STAGE(t+1 -> buf^1)  [3-4 gld_lds/wave, no wait]
//   COMPUTE(buf)         [4+NJ ds_read_b128 + 4*NJ MFMA]   <- loads fly under this
//   __syncthreads()      [compiler vmcnt(0)+lgkmcnt(0): staged data landed; buf readers done]
// vs the old {STAGE; sync; COMPUTE; sync} which drained just-issued loads with nothing
// overlapping (full staging latency exposed every tile). Same barriers per k-element,
// same staged bytes, LDS stays 2x(8+BN/16)KB (<=32 KB -> 3 blocks/CU preserved).
//
// LDS layout (BK=32): row = 64 B = 4 slots of 16 B. Slot s of row r holds global
// k-chunk s ^ ((r>>1)&3)  [XOR swizzle; 2-way bank aliasing = free per m136].
// Staging chunk = 16 rows (1 KB = one gld_lds16/wave): lane l -> row l>>2, slot l&3,
// pre-swizzled global k-chunk (l&3)^((l>>3)&3).
// Block mapping: plain 2-D, blockIdx.x = n-block fast (both XCD remaps regressed).
// K must be a multiple of 32.
template<int MODE, int BN>
__device__ __forceinline__
void gemm_body(const bf16* __restrict__ A, const bf16* __restrict__ BT,
               const float* __restrict__ bias, void* __restrict__ Cout,
               int M, int N, int K,
               const unsigned* __restrict__ trow, const unsigned* __restrict__ pact) {
    const int n0 = blockIdx.x * BN;
    const int m0 = blockIdx.y * 128;
    const int tid  = threadIdx.x;
    const int wave = tid >> 6;
    const int lane = tid & 63;

    constexpr int NJ  = BN / 32;       // B frags / acc cols per wave
    constexpr int BCH = BN / 16;       // B staging chunks (16 rows each)

    __shared__ __align__(16) bf16 As[2][128 * 32];   // 2 x 8 KB
    __shared__ __align__(16) bf16 Bs[2][BN * 32];    // 2 x 8 KB (BN=128) / 2 x 4 KB (BN=64)

    const int lrr = lane >> 2;                        // 0..15 row within 16-row chunk
    const int gkc = ((lane & 3) ^ ((lane >> 3) & 3)) * 8;  // pre-swizzled k offset (elems)
    const bf16* ag = A  + (size_t)(m0 + lrr) * K + gkc;
    const bf16* bg = BT + (size_t)(n0 + lrr) * K + gkc;

    f32x4 acc[4][NJ];
    #pragma unroll
    for (int i = 0; i < 4; i++)
        #pragma unroll
        for (int j = 0; j < NJ; j++) acc[i][j] = (f32x4){0.f, 0.f, 0.f, 0.f};

    const int rb = (wave >> 1) * 64;        // wave's m block within tile
    const int cb = (wave & 1) * (BN / 2);   // wave's n block within tile
    const int fr = lane & 15;
    const int kq = lane >> 4;               // 0..3: 8-elem k-chunk of the 32-k step

    // K-invariant fragment byte offsets: row r -> r*64 + (kq ^ ((r>>1)&3))*16;
    // (r>>1)&3 == (fr>>1)&3 since rb, i*16 are multiples of 8.
    const int sl = (kq ^ ((fr >> 1) & 3)) * 16;
    int aoff[4], boff[NJ];
    #pragma unroll
    for (int i = 0; i < 4; i++)  aoff[i] = (rb + i * 16 + fr) * 64 + sl;
    #pragma unroll
    for (int j = 0; j < NJ; j++) boff[j] = (cb + j * 16 + fr) * 64 + sl;

    const int NT = K >> 5;

    // stage one 32-k tile into buffer b: wave w covers A chunks {w, w+4},
    // B chunks {w, w+4} (only ch < BCH exist)
    auto STAGE = [&](int b, int k0) {
        #pragma unroll
        for (int q = 0; q < 2; q++) {
            const int ch = q * 4 + wave;              // wave-uniform chunk id
            gld_lds16(ag + (size_t)(ch * 16) * K + k0, &As[b][ch * 512]);
            if (ch < BCH)
                gld_lds16(bg + (size_t)(ch * 16) * K + k0, &Bs[b][ch * 512]);
        }
    };

    STAGE(0, 0);
    __syncthreads();                                  // tile 0 landed

    int buf = 0;
    for (int t = 0; t < NT; t++) {
        if (t + 1 < NT) STAGE(buf ^ 1, (t + 1) * 32); // issue next tile, no wait
        const char* Asb = (const char*)&As[buf][0];
        const char* Bsb = (const char*)&Bs[buf][0];
        short8 af[4], bfr[NJ];
        #pragma unroll
        for (int i = 0; i < 4; i++)  af[i]  = *(const short8*)(Asb + aoff[i]);
        #pragma unroll
        for (int j = 0; j < NJ; j++) bfr[j] = *(const short8*)(Bsb + boff[j]);
        #pragma unroll
        for (int i = 0; i < 4; i++)
            #pragma unroll
            for (int j = 0; j < NJ; j++)
                acc[i][j] = __builtin_amdgcn_mfma_f32_16x16x32_bf16(af[i], bfr[j], acc[i][j], 0, 0, 0);
        __syncthreads();                              // staged data landed; readers done
        buf ^= 1;
    }

    // C/D layout: col = lane&15, row = (lane>>4)*4 + r
    const int orow = m0 + rb + (lane >> 4) * 4;
    const int ocol = n0 + cb + fr;
    float bv[NJ];
    #pragma unroll
    for (int j = 0; j < NJ; j++) bv[j] = bias[ocol + j * 16];
    unsigned pv[NJ];
    if (MODE == 3) {
        #pragma unroll
        for (int j = 0; j < NJ; j++) pv[j] = pact[ocol + j * 16];
    }
    const unsigned H = 0x21084210u;   // guard bit (bit4) of each 5-bit field
    #pragma unroll
    for (int i = 0; i < 4; i++) {
        #pragma unroll
        for (int r = 0; r < 4; r++) {
            const int row = orow + i * 16 + r;
            unsigned TH = 0;
            if (MODE == 3) TH = trow[row] | H;
            #pragma unroll
            for (int j = 0; j < NJ; j++) {
                float val = acc[i][j][r] + bv[j];
                const size_t off = (size_t)row * N + ocol + j * 16;
                if (MODE == 0) {
                    ((bf16*)Cout)[off] = __float2bfloat16(tanhf(val));
                } else if (MODE == 3) {
                    // infeasible <=> some 5-bit field of pact exceeds trow field
                    if (((TH - pv[j]) & H) != H) val -= 20.7232658f;   // + log(1e-9)
                    ((bf16*)Cout)[off] = __float2bfloat16(val);
                } else {
                    ((bf16*)Cout)[off] = __float2bfloat16(val);
                }
            }
        }
    }
}

// distinct symbols per GEMM for rocprof attribution
__global__ __launch_bounds__(256)
void g1_gemm(const bf16* __restrict__ A, const bf16* __restrict__ BT,
             const float* __restrict__ bias, void* __restrict__ C, int M, int N, int K) {
    gemm_body<0, 64>(A, BT, bias, C, M, N, K, nullptr, nullptr);
}
__global__ __launch_bounds__(256)
void g2_gemm(const bf16* __restrict__ A, const bf16* __restrict__ BT,
             const float* __restrict__ bias, void* __restrict__ C, int M, int N, int K) {
    gemm_body<0, 64>(A, BT, bias, C, M, N, K, nullptr, nullptr);
}
__global__ __launch_bounds__(256)
void g3_gemm(const bf16* __restrict__ A, const bf16* __restrict__ BT,
             const float* __restrict__ bias, void* __restrict__ C, int M, int N, int K,
             const unsigned* __restrict__ trow, const unsigned* __restrict__ pact) {
    gemm_body<3, 128>(A, BT, bias, C, M, N, K, trow, pact);
}

// ---------------- softmax: bf16 (pre-masked) logits -> fp32 probs ----------------
// ONE WAVE PER ROW (4 rows per 256-thread block): zero barriers, zero LDS.
// No max-subtraction: logits bounded (|logit| <~ 30), exp fits fp32;
// mathematically identical to softmax (established round 3+, refchecked).
__global__ __launch_bounds__(256)
void softmax_k(const bf16* __restrict__ logitsb, float* __restrict__ out) {
    const int row  = (blockIdx.x << 2) | (threadIdx.x >> 6);   // wave id = row
    const int lane = threadIdx.x & 63;

    const unsigned* lrow = (const unsigned*)(logitsb + (size_t)row * NA);

    float v[64];
    float s = 0.f;
    #pragma unroll
    for (int c = 0; c < 8; c++) {
        u32x4 raw = *(const u32x4*)(lrow + c * 256 + lane * 4);
        #pragma unroll
        for (int e = 0; e < 4; e++) {
            float lo = __expf(__uint_as_float(raw[e] << 16));
            float hi = __expf(__uint_as_float(raw[e] & 0xffff0000u));
            v[c * 8 + 2 * e]     = lo;
            v[c * 8 + 2 * e + 1] = hi;
            s += lo + hi;
        }
    }
    #pragma unroll
    for (int o = 32; o > 0; o >>= 1) s += __shfl_xor(s, o, 64);
    const float inv = 1.0f / s;

    float* orow = out + (size_t)row * NA;
    #pragma unroll
    for (int c = 0; c < 8; c++) {
        const int fbase = c * 512 + lane * 8;
        #pragma unroll
        for (int q = 0; q < 2; q++) {
            f32x4 o4 = { v[c * 8 + q * 4] * inv,     v[c * 8 + q * 4 + 1] * inv,
                         v[c * 8 + q * 4 + 2] * inv, v[c * 8 + q * 4 + 3] * inv };
            *(f32x4*)(orow + fbase + q * 4) = o4;
        }
    }
}

// ---------------- launch ----------------
extern "C" void kernel_launch(void* const* d_in, const int* in_sizes, int n_in,
                              void* d_out, int out_size, void* d_ws, size_t ws_size,
                              hipStream_t stream) {
    const float* states = (const float*)d_in[0];
    const float* W1 = (const float*)d_in[1];
    const float* b1 = (const float*)d_in[2];
    const float* W2 = (const float*)d_in[3];
    const float* b2 = (const float*)d_in[4];
    const float* Wh = (const float*)d_in[5];
    const float* bh = (const float*)d_in[6];
    const int*   act = (const int*)d_in[7];
    float* out = (float*)d_out;

    char* ws = (char*)d_ws;
    bf16* statesb = (bf16*)ws; ws += (size_t)BATCH * KPAD * 2;
    bf16* w1bt    = (bf16*)ws; ws += (size_t)HID * KPAD * 2;
    bf16* w2bt    = (bf16*)ws; ws += (size_t)HID * HID * 2;
    bf16* whbt    = (bf16*)ws; ws += (size_t)NA * HID * 2;
    bf16* h1      = (bf16*)ws; ws += (size_t)BATCH * HID * 2;
    bf16* h2      = (bf16*)ws; ws += (size_t)BATCH * HID * 2;
    bf16* logitsb = (bf16*)ws; ws += (size_t)BATCH * NA * 2;
    unsigned* pact = (unsigned*)ws; ws += (size_t)NA * 4;
    unsigned* trow = (unsigned*)ws; ws += (size_t)BATCH * 4;

    prep_k<<<5808, 256, 0, stream>>>(states, W1, W2, Wh, act,
                                     statesb, w1bt, w2bt, whbt, pact, trow);

    // G1/G2: N=1024 -> BN=64 tiles (1024 blocks; occupancy fix, round 6: -24 us)
    g1_gemm<<<dim3(HID / 64, BATCH / 128), 256, 0, stream>>>(
        statesb, w1bt, b1, h1, BATCH, HID, KPAD);
    g2_gemm<<<dim3(HID / 64, BATCH / 128), 256, 0, stream>>>(
        h1, w2bt, b2, h2, BATCH, HID, HID);
    // logits GEMM with fused feasibility log-mask in the epilogue
    g3_gemm<<<dim3(NA / 128, BATCH / 128), 256, 0, stream>>>(
        h2, whbt, bh, logitsb, BATCH, NA, HID, trow, pact);

    softmax_k<<<BATCH / 4, 256, 0, stream>>>(logitsb, out);
}

// Round 10
// 300.746 us; speedup vs baseline: 1.0588x; 1.0588x over previous
//
#include <hip/hip_runtime.h>
#include <hip/hip_bf16.h>
#include <math.h>

using bf16 = __hip_bfloat16;
typedef __attribute__((ext_vector_type(8))) short short8;
typedef __attribute__((ext_vector_type(4))) float f32x4;
typedef __attribute__((ext_vector_type(4))) unsigned int u32x4;

#define BATCH 8192
#define SDIM  70
#define NS    64
#define HID   1024
#define NA    4096
#define KPAD  128   // states K padded 70 -> 128 (multiple of 64 for BK=64)

// async global->LDS, 16 B per lane. LDS dest is wave-uniform base + lane*16.
__device__ __forceinline__ void gld_lds16(const bf16* g, bf16* l) {
    __builtin_amdgcn_global_load_lds(
        (const __attribute__((address_space(1))) void*)g,
        (__attribute__((address_space(3))) void*)l, 16, 0, 0);
}

__device__ __forceinline__ short f2bf(float v) {
    union { bf16 b; short s; } u; u.b = __float2bfloat16(v); return u.s;
}

// ---------------- fused prep kernel ----------------
// block ranges:
//   [0,512)       : states fp32[8192][70] -> bf16[8192][128] zero-padded (8 cols/thread)
//   [512,640)     : W1 [70][1024]   -> w1bt [1024][128]
//   [640,1664)    : W2 [1024][1024] -> w2bt [1024][1024]
//   [1664,5760)   : Wh [1024][4096] -> whbt [4096][1024]
//   [5760,5776)   : pact (5-bit x6 SWAR pack of action_space)
//   [5776,5808)   : trow (5-bit x6 SWAR pack of floor(waitlist) per batch row)
__device__ __forceinline__ void tr32(const float* __restrict__ in, bf16* __restrict__ out,
                                     int K, int N, int Kpad, int bx, int by, int t,
                                     float (*tile)[33]) {
    int kb = by * 32, nb = bx * 32;
    int tx = t & 31, ty = t >> 5;
    #pragma unroll
    for (int i = 0; i < 32; i += 8) {
        int k = kb + ty + i, n = nb + tx;
        tile[ty + i][tx] = (k < K) ? in[(size_t)k * N + n] : 0.0f;
    }
    __syncthreads();
    #pragma unroll
    for (int i = 0; i < 32; i += 8) {
        int n = nb + ty + i, k = kb + tx;
        if (k < Kpad) out[(size_t)n * Kpad + k] = __float2bfloat16(tile[tx][ty + i]);
    }
}

__global__ __launch_bounds__(256)
void prep_k(const float* __restrict__ states, const float* __restrict__ W1,
            const float* __restrict__ W2, const float* __restrict__ Wh,
            const int* __restrict__ act,
            bf16* __restrict__ statesb, bf16* __restrict__ w1bt,
            bf16* __restrict__ w2bt, bf16* __restrict__ whbt,
            unsigned* __restrict__ pact, unsigned* __restrict__ trow) {
    __shared__ float tile[32][33];
    const int b = blockIdx.x, t = threadIdx.x;
    if (b < 512) {
        int idx = b * 256 + t;                 // 131072 threads, 8 cols each
        int row = idx >> 4;                    // 16 threads per row
        int c0  = (idx & 15) * 8;
        const float* src = states + (size_t)row * SDIM;
        short8 o;
        #pragma unroll
        for (int i = 0; i < 8; i++) {
            int c = c0 + i;
            o[i] = f2bf((c < SDIM) ? src[c] : 0.0f);
        }
        *(short8*)&statesb[(size_t)row * KPAD + c0] = o;
    } else if (b < 640) {
        int r = b - 512;                       // 32 nb x 4 kb
        tr32(W1, w1bt, SDIM, HID, KPAD, r & 31, r >> 5, t, tile);
    } else if (b < 1664) {
        int r = b - 640;                       // 32 x 32
        tr32(W2, w2bt, HID, HID, HID, r & 31, r >> 5, t, tile);
    } else if (b < 5760) {
        int r = b - 1664;                      // 128 nb x 32 kb
        tr32(Wh, whbt, HID, NA, HID, r & 127, r >> 7, t, tile);
    } else if (b < 5776) {
        int c = (b - 5760) * 256 + t;
        if (c < NA) {
            const int* a = act + c * 6;
            unsigned p = 0;
            #pragma unroll
            for (int i = 0; i < 6; i++) p |= ((unsigned)a[i]) << (5 * i);
            pact[c] = p;
        }
    } else {
        int row = (b - 5776) * 256 + t;        // 32*256 = 8192 rows exactly
        const float* wl = states + (size_t)row * SDIM + NS;
        unsigned T = 0;
        #pragma unroll
        for (int i = 0; i < 6; i++) T |= ((unsigned)(int)wl[i]) << (5 * i);
        trow[row] = T;
    }
}

// ---------------- bf16 MFMA GEMM body: 128xBN tile, BK=64, swizzled LDS ----------------
// C[M][N] = epilogue(A[M][K] @ BT[N][K]^T + bias)
// MODE 0: tanh -> bf16; MODE 3: raw + log-mask (SWAR feasibility) -> bf16
// BN = 128: 4 waves, wave tile 64x64, acc[4][4]  (grid-rich dispatches)
// BN = 64 : 4 waves, wave tile 64x32, acc[4][2]  (2x blocks for occupancy-starved
//           N=1024 dispatches: 512 -> 1024 blocks, LDS 32 -> 24 KB)
//
// STRUCTURE LEDGER (do not re-try):
//   r1/r2: 256^2 8-phase & 4-phase ports     -> 131 / ~114 us (revert)
//   r5: XCD-chunked N-major remap            -> FETCH 82 -> 267 MB (revert)
//   r7: exp+rowsum fused epilogue            -> +12 us (revert)
//   r9: BK=32 2-phase double-buffer          -> G3 83 -> 98 us (revert; 64-B
//       staging segments double L2 requests; barrier still drains t+1 loads)
// This BK=64 single-buffer {STAGE; sync; COMPUTE; sync} body measured best
// (r8: total 294.6 us, G3 <= ~83 us ~ 830 TF = the m97-structure plateau).
// Block mapping: plain 2-D, blockIdx.x = n-block fast (A-panel L2 reuse).
// LDS layout: row r (128 B = 8 chunks of 16 B); slot c holds global k-chunk c^(r&7).
// K must be a multiple of 64.
template<int MODE, int BN>
__device__ __forceinline__
void gemm_body(const bf16* __restrict__ A, const bf16* __restrict__ BT,
               const float* __restrict__ bias, void* __restrict__ Cout,
               int M, int N, int K,
               const unsigned* __restrict__ trow, const unsigned* __restrict__ pact) {
    const int n0 = blockIdx.x * BN;
    const int m0 = blockIdx.y * 128;
    const int tid  = threadIdx.x;
    const int wave = tid >> 6;
    const int lane = tid & 63;

    constexpr int NJ  = BN / 32;       // acc cols per wave
    constexpr int BCH = BN / 8;        // 8-row staging chunks in B

    __shared__ __align__(16) bf16 As[128 * 64];   // 16 KB
    __shared__ __align__(16) bf16 Bs[BN * 64];    // 16 KB (BN=128) / 8 KB (BN=64)

    // staging: round q, wave w -> 8-row chunk (q*4+w); lane l -> row +(l>>3),
    // LDS slot (l&7); global k-chunk (l&7)^(l>>3)  [XOR swizzle]
    const int lr = lane >> 3;                     // 0..7
    const int gk = ((lane & 7) ^ lr) * 8;         // swizzled global k offset
    const bf16* ag = A  + (size_t)(m0 + lr) * K + gk;
    const bf16* bg = BT + (size_t)(n0 + lr) * K + gk;

    f32x4 acc[4][NJ];
    #pragma unroll
    for (int i = 0; i < 4; i++)
        #pragma unroll
        for (int j = 0; j < NJ; j++) acc[i][j] = (f32x4){0.f, 0.f, 0.f, 0.f};

    const int rb = (wave >> 1) * 64;        // wave's m block within tile
    const int cb = (wave & 1) * (BN / 2);   // wave's n block within tile
    const int fr = lane & 15;
    const int kq = lane >> 4;               // 0..3: which 8-elem chunk of the 32-k step

    // K-invariant LDS fragment byte offsets (r&7 == fr&7 since rb,i*16 are mult of 8)
    int aoff[2][4], boff[2][NJ];
    #pragma unroll
    for (int kk = 0; kk < 2; kk++) {
        const int cbase = kk * 4 + kq;
        #pragma unroll
        for (int i = 0; i < 4; i++) {
            const int ra = rb + i * 16 + fr;
            aoff[kk][i] = (ra * 64 + ((cbase ^ (fr & 7)) * 8)) * 2;
        }
        #pragma unroll
        for (int j = 0; j < NJ; j++) {
            const int rn = cb + j * 16 + fr;
            boff[kk][j] = (rn * 64 + ((cbase ^ (fr & 7)) * 8)) * 2;
        }
    }
    const char* Asb = (const char*)As;
    const char* Bsb = (const char*)Bs;

    for (int k0 = 0; k0 < K; k0 += 64) {
        #pragma unroll
        for (int q = 0; q < 4; q++) {
            const int ch = q * 4 + wave;          // 8-row chunk id (wave-uniform)
            gld_lds16(ag + (size_t)(ch * 8) * K + k0, &As[ch * 512]);
            if (ch < BCH)
                gld_lds16(bg + (size_t)(ch * 8) * K + k0, &Bs[ch * 512]);
        }
        __syncthreads();

        #pragma unroll
        for (int kk = 0; kk < 2; kk++) {          // two 32-k MFMA steps
            short8 af[4], bfr[NJ];
            #pragma unroll
            for (int i = 0; i < 4; i++)  af[i]  = *(const short8*)(Asb + aoff[kk][i]);
            #pragma unroll
            for (int j = 0; j < NJ; j++) bfr[j] = *(const short8*)(Bsb + boff[kk][j]);
            #pragma unroll
            for (int i = 0; i < 4; i++)
                #pragma unroll
                for (int j = 0; j < NJ; j++)
                    acc[i][j] = __builtin_amdgcn_mfma_f32_16x16x32_bf16(af[i], bfr[j], acc[i][j], 0, 0, 0);
        }
        __syncthreads();
    }

    // C/D layout: col = lane&15, row = (lane>>4)*4 + r
    const int orow = m0 + rb + (lane >> 4) * 4;
    const int ocol = n0 + cb + fr;
    float bv[NJ];
    #pragma unroll
    for (int j = 0; j < NJ; j++) bv[j] = bias[ocol + j * 16];
    unsigned pv[NJ];
    if (MODE == 3) {
        #pragma unroll
        for (int j = 0; j < NJ; j++) pv[j] = pact[ocol + j * 16];
    }
    const unsigned H = 0x21084210u;   // guard bit (bit4) of each 5-bit field
    #pragma unroll
    for (int i = 0; i < 4; i++) {
        #pragma unroll
        for (int r = 0; r < 4; r++) {
            const int row = orow + i * 16 + r;
            unsigned TH = 0;
            if (MODE == 3) TH = trow[row] | H;
            #pragma unroll
            for (int j = 0; j < NJ; j++) {
                float val = acc[i][j][r] + bv[j];
                const size_t off = (size_t)row * N + ocol + j * 16;
                if (MODE == 0) {
                    ((bf16*)Cout)[off] = __float2bfloat16(tanhf(val));
                } else if (MODE == 3) {
                    // infeasible <=> some 5-bit field of pact exceeds trow field
                    if (((TH - pv[j]) & H) != H) val -= 20.7232658f;   // + log(1e-9)
                    ((bf16*)Cout)[off] = __float2bfloat16(val);
                } else {
                    ((bf16*)Cout)[off] = __float2bfloat16(val);
                }
            }
        }
    }
}

// distinct symbols per GEMM for rocprof attribution
__global__ __launch_bounds__(256)
void g1_gemm(const bf16* __restrict__ A, const bf16* __restrict__ BT,
             const float* __restrict__ bias, void* __restrict__ C, int M, int N, int K) {
    gemm_body<0, 64>(A, BT, bias, C, M, N, K, nullptr, nullptr);
}
__global__ __launch_bounds__(256)
void g2_gemm(const bf16* __restrict__ A, const bf16* __restrict__ BT,
             const float* __restrict__ bias, void* __restrict__ C, int M, int N, int K) {
    gemm_body<0, 64>(A, BT, bias, C, M, N, K, nullptr, nullptr);
}
__global__ __launch_bounds__(256)
void g3_gemm(const bf16* __restrict__ A, const bf16* __restrict__ BT,
             const float* __restrict__ bias, void* __restrict__ C, int M, int N, int K,
             const unsigned* __restrict__ trow, const unsigned* __restrict__ pact) {
    gemm_body<3, 128>(A, BT, bias, C, M, N, K, trow, pact);
}

// ---------------- softmax: bf16 (pre-masked) logits -> fp32 probs ----------------
// ONE WAVE PER ROW (4 rows per 256-thread block): zero barriers, zero LDS.
// No max-subtraction: logits bounded (|logit| <~ 30), exp fits fp32;
// mathematically identical to softmax (established round 3+, refchecked).
__global__ __launch_bounds__(256)
void softmax_k(const bf16* __restrict__ logitsb, float* __restrict__ out) {
    const int row  = (blockIdx.x << 2) | (threadIdx.x >> 6);   // wave id = row
    const int lane = threadIdx.x & 63;

    const unsigned* lrow = (const unsigned*)(logitsb + (size_t)row * NA);

    float v[64];
    float s = 0.f;
    #pragma unroll
    for (int c = 0; c < 8; c++) {
        u32x4 raw = *(const u32x4*)(lrow + c * 256 + lane * 4);
        #pragma unroll
        for (int e = 0; e < 4; e++) {
            float lo = __expf(__uint_as_float(raw[e] << 16));
            float hi = __expf(__uint_as_float(raw[e] & 0xffff0000u));
            v[c * 8 + 2 * e]     = lo;
            v[c * 8 + 2 * e + 1] = hi;
            s += lo + hi;
        }
    }
    #pragma unroll
    for (int o = 32; o > 0; o >>= 1) s += __shfl_xor(s, o, 64);
    const float inv = 1.0f / s;

    float* orow = out + (size_t)row * NA;
    #pragma unroll
    for (int c = 0; c < 8; c++) {
        const int fbase = c * 512 + lane * 8;
        #pragma unroll
        for (int q = 0; q < 2; q++) {
            f32x4 o4 = { v[c * 8 + q * 4] * inv,     v[c * 8 + q * 4 + 1] * inv,
                         v[c * 8 + q * 4 + 2] * inv, v[c * 8 + q * 4 + 3] * inv };
            *(f32x4*)(orow + fbase + q * 4) = o4;
        }
    }
}

// ---------------- launch ----------------
extern "C" void kernel_launch(void* const* d_in, const int* in_sizes, int n_in,
                              void* d_out, int out_size, void* d_ws, size_t ws_size,
                              hipStream_t stream) {
    const float* states = (const float*)d_in[0];
    const float* W1 = (const float*)d_in[1];
    const float* b1 = (const float*)d_in[2];
    const float* W2 = (const float*)d_in[3];
    const float* b2 = (const float*)d_in[4];
    const float* Wh = (const float*)d_in[5];
    const float* bh = (const float*)d_in[6];
    const int*   act = (const int*)d_in[7];
    float* out = (float*)d_out;

    char* ws = (char*)d_ws;
    bf16* statesb = (bf16*)ws; ws += (size_t)BATCH * KPAD * 2;
    bf16* w1bt    = (bf16*)ws; ws += (size_t)HID * KPAD * 2;
    bf16* w2bt    = (bf16*)ws; ws += (size_t)HID * HID * 2;
    bf16* whbt    = (bf16*)ws; ws += (size_t)NA * HID * 2;
    bf16* h1      = (bf16*)ws; ws += (size_t)BATCH * HID * 2;
    bf16* h2      = (bf16*)ws; ws += (size_t)BATCH * HID * 2;
    bf16* logitsb = (bf16*)ws; ws += (size_t)BATCH * NA * 2;
    unsigned* pact = (unsigned*)ws; ws += (size_t)NA * 4;
    unsigned* trow = (unsigned*)ws; ws += (size_t)BATCH * 4;

    prep_k<<<5808, 256, 0, stream>>>(states, W1, W2, Wh, act,
                                     statesb, w1bt, w2bt, whbt, pact, trow);

    // G1/G2: N=1024 -> BN=64 tiles (1024 blocks; occupancy fix, round 6: -24 us)
    g1_gemm<<<dim3(HID / 64, BATCH / 128), 256, 0, stream>>>(
        statesb, w1bt, b1, h1, BATCH, HID, KPAD);
    g2_gemm<<<dim3(HID / 64, BATCH / 128), 256, 0, stream>>>(
        h1, w2bt, b2, h2, BATCH, HID, HID);
    // logits GEMM with fused feasibility log-mask in the epilogue
    g3_gemm<<<dim3(NA / 128, BATCH / 128), 256, 0, stream>>>(
        h2, whbt, bh, logitsb, BATCH, NA, HID, trow, pact);

    softmax_k<<<BATCH / 4, 256, 0, stream>>>(logitsb, out);
}

// Round 11
// 298.905 us; speedup vs baseline: 1.0653x; 1.0062x over previous
//
#include <hip/hip_runtime.h>
#include <hip/hip_bf16.h>
#include <math.h>

using bf16 = __hip_bfloat16;
typedef __attribute__((ext_vector_type(8))) short short8;
typedef __attribute__((ext_vector_type(4))) float f32x4;
typedef __attribute__((ext_vector_type(4))) unsigned int u32x4;

#define BATCH 8192
#define SDIM  70
#define NS    64
#define HID   1024
#define NA    4096
#define KPAD  128   // states K padded 70 -> 128 (multiple of 64 for BK=64)

// async global->LDS, 16 B per lane. LDS dest is wave-uniform base + lane*16.
__device__ __forceinline__ void gld_lds16(const bf16* g, bf16* l) {
    __builtin_amdgcn_global_load_lds(
        (const __attribute__((address_space(1))) void*)g,
        (__attribute__((address_space(3))) void*)l, 16, 0, 0);
}

__device__ __forceinline__ short f2bf(float v) {
    union { bf16 b; short s; } u; u.b = __float2bfloat16(v); return u.s;
}

// ---------------- fused prep kernel ----------------
// block ranges:
//   [0,512)       : states fp32[8192][70] -> bf16[8192][128] zero-padded (8 cols/thread)
//   [512,640)     : W1 [70][1024]   -> w1bt [1024][128]
//   [640,1664)    : W2 [1024][1024] -> w2bt [1024][1024]
//   [1664,5760)   : Wh [1024][4096] -> whbt [4096][1024]
//   [5760,5776)   : pact (5-bit x6 SWAR pack of action_space)
//   [5776,5808)   : trow (5-bit x6 SWAR pack of floor(waitlist) per batch row)
__device__ __forceinline__ void tr32(const float* __restrict__ in, bf16* __restrict__ out,
                                     int K, int N, int Kpad, int bx, int by, int t,
                                     float (*tile)[33]) {
    int kb = by * 32, nb = bx * 32;
    int tx = t & 31, ty = t >> 5;
    #pragma unroll
    for (int i = 0; i < 32; i += 8) {
        int k = kb + ty + i, n = nb + tx;
        tile[ty + i][tx] = (k < K) ? in[(size_t)k * N + n] : 0.0f;
    }
    __syncthreads();
    #pragma unroll
    for (int i = 0; i < 32; i += 8) {
        int n = nb + ty + i, k = kb + tx;
        if (k < Kpad) out[(size_t)n * Kpad + k] = __float2bfloat16(tile[tx][ty + i]);
    }
}

__global__ __launch_bounds__(256)
void prep_k(const float* __restrict__ states, const float* __restrict__ W1,
            const float* __restrict__ W2, const float* __restrict__ Wh,
            const int* __restrict__ act,
            bf16* __restrict__ statesb, bf16* __restrict__ w1bt,
            bf16* __restrict__ w2bt, bf16* __restrict__ whbt,
            unsigned* __restrict__ pact, unsigned* __restrict__ trow) {
    __shared__ float tile[32][33];
    const int b = blockIdx.x, t = threadIdx.x;
    if (b < 512) {
        int idx = b * 256 + t;                 // 131072 threads, 8 cols each
        int row = idx >> 4;                    // 16 threads per row
        int c0  = (idx & 15) * 8;
        const float* src = states + (size_t)row * SDIM;
        short8 o;
        #pragma unroll
        for (int i = 0; i < 8; i++) {
            int c = c0 + i;
            o[i] = f2bf((c < SDIM) ? src[c] : 0.0f);
        }
        *(short8*)&statesb[(size_t)row * KPAD + c0] = o;
    } else if (b < 640) {
        int r = b - 512;                       // 32 nb x 4 kb
        tr32(W1, w1bt, SDIM, HID, KPAD, r & 31, r >> 5, t, tile);
    } else if (b < 1664) {
        int r = b - 640;                       // 32 x 32
        tr32(W2, w2bt, HID, HID, HID, r & 31, r >> 5, t, tile);
    } else if (b < 5760) {
        int r = b - 1664;                      // 128 nb x 32 kb
        tr32(Wh, whbt, HID, NA, HID, r & 127, r >> 7, t, tile);
    } else if (b < 5776) {
        int c = (b - 5760) * 256 + t;
        if (c < NA) {
            const int* a = act + c * 6;
            unsigned p = 0;
            #pragma unroll
            for (int i = 0; i < 6; i++) p |= ((unsigned)a[i]) << (5 * i);
            pact[c] = p;
        }
    } else {
        int row = (b - 5776) * 256 + t;        // 32*256 = 8192 rows exactly
        const float* wl = states + (size_t)row * SDIM + NS;
        unsigned T = 0;
        #pragma unroll
        for (int i = 0; i < 6; i++) T |= ((unsigned)(int)wl[i]) << (5 * i);
        trow[row] = T;
    }
}

// ---------------- bf16 MFMA GEMM body: 128xBN tile, BK=64, swizzled LDS ----------------
// C[M][N] = epilogue(A[M][K] @ BT[N][K]^T + bias)
// MODE 0: tanh -> bf16; MODE 3: raw + log-mask (SWAR feasibility) -> bf16
// BN = 128: 4 waves, wave tile 64x64, acc[4][4]; BN = 64: wave tile 64x32, acc[4][2].
//
// r11 change (single mechanism): moved the STAGE issue point. Old loop issued
// STAGE(t) immediately before the barrier whose implicit vmcnt(0) drained it with
// ZERO flight time (full L2/L3 staging latency serialized into every K-tile). New:
//   barrier1   (tile t landed -- drains the STAGE issued last iteration)
//   ds_read all 16 frags (both kk)        <- must ALL be read before barrier2
//   barrier2   (compiler lgkmcnt(0): every wave's frags are in VGPRs)
//   STAGE(t+1) (overwrites the single buffer -- race-free; flies under MFMAs)
//   sched_barrier(0)  (pin gld issue before the MFMA cluster)
//   32 MFMAs
// Same 2 barriers/tile, same bytes, same 16/32 KB LDS. Costs +32 VGPR (held frags).
//
// STRUCTURE LEDGER (do not re-try):
//   r1/r2: 256^2 8-phase & 4-phase ports     -> 131 / ~114 us (revert)
//   r5: XCD-chunked N-major remap            -> FETCH 82 -> 267 MB (revert)
//   r7: exp+rowsum fused epilogue            -> +12 us (revert)
//   r9: BK=32 2-phase double-buffer          -> G3 83 -> 98 us (revert)
//   r8/r10 baseline: G3 86.5 us, MfmaUtil 33%, ~794 TF (m97-template plateau)
// Block mapping: plain 2-D, blockIdx.x = n-block fast (A-panel L2 reuse).
// LDS layout: row r (128 B = 8 chunks of 16 B); slot c holds global k-chunk c^(r&7).
// K must be a multiple of 64.
template<int MODE, int BN>
__device__ __forceinline__
void gemm_body(const bf16* __restrict__ A, const bf16* __restrict__ BT,
               const float* __restrict__ bias, void* __restrict__ Cout,
               int M, int N, int K,
               const unsigned* __restrict__ trow, const unsigned* __restrict__ pact) {
    const int n0 = blockIdx.x * BN;
    const int m0 = blockIdx.y * 128;
    const int tid  = threadIdx.x;
    const int wave = tid >> 6;
    const int lane = tid & 63;

    constexpr int NJ  = BN / 32;       // acc cols per wave
    constexpr int BCH = BN / 8;        // 8-row staging chunks in B

    __shared__ __align__(16) bf16 As[128 * 64];   // 16 KB
    __shared__ __align__(16) bf16 Bs[BN * 64];    // 16 KB (BN=128) / 8 KB (BN=64)

    // staging: round q, wave w -> 8-row chunk (q*4+w); lane l -> row +(l>>3),
    // LDS slot (l&7); global k-chunk (l&7)^(l>>3)  [XOR swizzle]
    const int lr = lane >> 3;                     // 0..7
    const int gk = ((lane & 7) ^ lr) * 8;         // swizzled global k offset
    const bf16* ag = A  + (size_t)(m0 + lr) * K + gk;
    const bf16* bg = BT + (size_t)(n0 + lr) * K + gk;

    f32x4 acc[4][NJ];
    #pragma unroll
    for (int i = 0; i < 4; i++)
        #pragma unroll
        for (int j = 0; j < NJ; j++) acc[i][j] = (f32x4){0.f, 0.f, 0.f, 0.f};

    const int rb = (wave >> 1) * 64;        // wave's m block within tile
    const int cb = (wave & 1) * (BN / 2);   // wave's n block within tile
    const int fr = lane & 15;
    const int kq = lane >> 4;               // 0..3: which 8-elem chunk of the 32-k step

    // K-invariant LDS fragment byte offsets (r&7 == fr&7 since rb,i*16 are mult of 8)
    int aoff[2][4], boff[2][NJ];
    #pragma unroll
    for (int kk = 0; kk < 2; kk++) {
        const int cbase = kk * 4 + kq;
        #pragma unroll
        for (int i = 0; i < 4; i++) {
            const int ra = rb + i * 16 + fr;
            aoff[kk][i] = (ra * 64 + ((cbase ^ (fr & 7)) * 8)) * 2;
        }
        #pragma unroll
        for (int j = 0; j < NJ; j++) {
            const int rn = cb + j * 16 + fr;
            boff[kk][j] = (rn * 64 + ((cbase ^ (fr & 7)) * 8)) * 2;
        }
    }
    const char* Asb = (const char*)As;
    const char* Bsb = (const char*)Bs;

    // stage one 64-k tile (8 loads/wave for BN=128, 6 for BN=64)
    auto STAGE = [&](int k0) {
        #pragma unroll
        for (int q = 0; q < 4; q++) {
            const int ch = q * 4 + wave;          // 8-row chunk id (wave-uniform)
            gld_lds16(ag + (size_t)(ch * 8) * K + k0, &As[ch * 512]);
            if (ch < BCH)
                gld_lds16(bg + (size_t)(ch * 8) * K + k0, &Bs[ch * 512]);
        }
    };

    STAGE(0);
    for (int k0 = 0; k0 < K; k0 += 64) {
        __syncthreads();                          // tile k0 landed (vmcnt drain of STAGE)

        short8 af[2][4], bfr[2][NJ];
        #pragma unroll
        for (int kk = 0; kk < 2; kk++) {
            #pragma unroll
            for (int i = 0; i < 4; i++)  af[kk][i]  = *(const short8*)(Asb + aoff[kk][i]);
            #pragma unroll
            for (int j = 0; j < NJ; j++) bfr[kk][j] = *(const short8*)(Bsb + boff[kk][j]);
        }
        __syncthreads();                          // all waves' frags in VGPRs (lgkm drain)

        if (k0 + 64 < K) STAGE(k0 + 64);          // overwrite buffer; loads fly under MFMAs
        __builtin_amdgcn_sched_barrier(0);        // pin gld issue ahead of MFMA cluster

        #pragma unroll
        for (int kk = 0; kk < 2; kk++)
            #pragma unroll
            for (int i = 0; i < 4; i++)
                #pragma unroll
                for (int j = 0; j < NJ; j++)
                    acc[i][j] = __builtin_amdgcn_mfma_f32_16x16x32_bf16(
                        af[kk][i], bfr[kk][j], acc[i][j], 0, 0, 0);
    }

    // C/D layout: col = lane&15, row = (lane>>4)*4 + r
    const int orow = m0 + rb + (lane >> 4) * 4;
    const int ocol = n0 + cb + fr;
    float bv[NJ];
    #pragma unroll
    for (int j = 0; j < NJ; j++) bv[j] = bias[ocol + j * 16];
    unsigned pv[NJ];
    if (MODE == 3) {
        #pragma unroll
        for (int j = 0; j < NJ; j++) pv[j] = pact[ocol + j * 16];
    }
    const unsigned H = 0x21084210u;   // guard bit (bit4) of each 5-bit field
    #pragma unroll
    for (int i = 0; i < 4; i++) {
        #pragma unroll
        for (int r = 0; r < 4; r++) {
            const int row = orow + i * 16 + r;
            unsigned TH = 0;
            if (MODE == 3) TH = trow[row] | H;
            #pragma unroll
            for (int j = 0; j < NJ; j++) {
                float val = acc[i][j][r] + bv[j];
                const size_t off = (size_t)row * N + ocol + j * 16;
                if (MODE == 0) {
                    ((bf16*)Cout)[off] = __float2bfloat16(tanhf(val));
                } else if (MODE == 3) {
                    // infeasible <=> some 5-bit field of pact exceeds trow field
                    if (((TH - pv[j]) & H) != H) val -= 20.7232658f;   // + log(1e-9)
                    ((bf16*)Cout)[off] = __float2bfloat16(val);
                } else {
                    ((bf16*)Cout)[off] = __float2bfloat16(val);
                }
            }
        }
    }
}

// distinct symbols per GEMM for rocprof attribution
__global__ __launch_bounds__(256)
void g1_gemm(const bf16* __restrict__ A, const bf16* __restrict__ BT,
             const float* __restrict__ bias, void* __restrict__ C, int M, int N, int K) {
    gemm_body<0, 64>(A, BT, bias, C, M, N, K, nullptr, nullptr);
}
__global__ __launch_bounds__(256)
void g2_gemm(const bf16* __restrict__ A, const bf16* __restrict__ BT,
             const float* __restrict__ bias, void* __restrict__ C, int M, int N, int K) {
    gemm_body<0, 64>(A, BT, bias, C, M, N, K, nullptr, nullptr);
}
__global__ __launch_bounds__(256)
void g3_gemm(const bf16* __restrict__ A, const bf16* __restrict__ BT,
             const float* __restrict__ bias, void* __restrict__ C, int M, int N, int K,
             const unsigned* __restrict__ trow, const unsigned* __restrict__ pact) {
    gemm_body<3, 128>(A, BT, bias, C, M, N, K, trow, pact);
}

// ---------------- softmax: bf16 (pre-masked) logits -> fp32 probs ----------------
// ONE WAVE PER ROW (4 rows per 256-thread block): zero barriers, zero LDS.
// No max-subtraction: logits bounded (|logit| <~ 30), exp fits fp32;
// mathematically identical to softmax (established round 3+, refchecked).
__global__ __launch_bounds__(256)
void softmax_k(const bf16* __restrict__ logitsb, float* __restrict__ out) {
    const int row  = (blockIdx.x << 2) | (threadIdx.x >> 6);   // wave id = row
    const int lane = threadIdx.x & 63;

    const unsigned* lrow = (const unsigned*)(logitsb + (size_t)row * NA);

    float v[64];
    float s = 0.f;
    #pragma unroll
    for (int c = 0; c < 8; c++) {
        u32x4 raw = *(const u32x4*)(lrow + c * 256 + lane * 4);
        #pragma unroll
        for (int e = 0; e < 4; e++) {
            float lo = __expf(__uint_as_float(raw[e] << 16));
            float hi = __expf(__uint_as_float(raw[e] & 0xffff0000u));
            v[c * 8 + 2 * e]     = lo;
            v[c * 8 + 2 * e + 1] = hi;
            s += lo + hi;
        }
    }
    #pragma unroll
    for (int o = 32; o > 0; o >>= 1) s += __shfl_xor(s, o, 64);
    const float inv = 1.0f / s;

    float* orow = out + (size_t)row * NA;
    #pragma unroll
    for (int c = 0; c < 8; c++) {
        const int fbase = c * 512 + lane * 8;
        #pragma unroll
        for (int q = 0; q < 2; q++) {
            f32x4 o4 = { v[c * 8 + q * 4] * inv,     v[c * 8 + q * 4 + 1] * inv,
                         v[c * 8 + q * 4 + 2] * inv, v[c * 8 + q * 4 + 3] * inv };
            *(f32x4*)(orow + fbase + q * 4) = o4;
        }
    }
}

// ---------------- launch ----------------
extern "C" void kernel_launch(void* const* d_in, const int* in_sizes, int n_in,
                              void* d_out, int out_size, void* d_ws, size_t ws_size,
                              hipStream_t stream) {
    const float* states = (const float*)d_in[0];
    const float* W1 = (const float*)d_in[1];
    const float* b1 = (const float*)d_in[2];
    const float* W2 = (const float*)d_in[3];
    const float* b2 = (const float*)d_in[4];
    const float* Wh = (const float*)d_in[5];
    const float* bh = (const float*)d_in[6];
    const int*   act = (const int*)d_in[7];
    float* out = (float*)d_out;

    char* ws = (char*)d_ws;
    bf16* statesb = (bf16*)ws; ws += (size_t)BATCH * KPAD * 2;
    bf16* w1bt    = (bf16*)ws; ws += (size_t)HID * KPAD * 2;
    bf16* w2bt    = (bf16*)ws; ws += (size_t)HID * HID * 2;
    bf16* whbt    = (bf16*)ws; ws += (size_t)NA * HID * 2;
    bf16* h1      = (bf16*)ws; ws += (size_t)BATCH * HID * 2;
    bf16* h2      = (bf16*)ws; ws += (size_t)BATCH * HID * 2;
    bf16* logitsb = (bf16*)ws; ws += (size_t)BATCH * NA * 2;
    unsigned* pact = (unsigned*)ws; ws += (size_t)NA * 4;
    unsigned* trow = (unsigned*)ws; ws += (size_t)BATCH * 4;

    prep_k<<<5808, 256, 0, stream>>>(states, W1, W2, Wh, act,
                                     statesb, w1bt, w2bt, whbt, pact, trow);

    // G1/G2: N=1024 -> BN=64 tiles (1024 blocks; occupancy fix, round 6: -24 us)
    g1_gemm<<<dim3(HID / 64, BATCH / 128), 256, 0, stream>>>(
        statesb, w1bt, b1, h1, BATCH, HID, KPAD);
    g2_gemm<<<dim3(HID / 64, BATCH / 128), 256, 0, stream>>>(
        h1, w2bt, b2, h2, BATCH, HID, HID);
    // logits GEMM with fused feasibility log-mask in the epilogue
    g3_gemm<<<dim3(NA / 128, BATCH / 128), 256, 0, stream>>>(
        h2, whbt, bh, logitsb, BATCH, NA, HID, trow, pact);

    softmax_k<<<BATCH / 4, 256, 0, stream>>>(logitsb, out);
}